// Round 3
// baseline (498.995 us; speedup 1.0000x reference)
//
#include <hip/hip_runtime.h>
#include <hip/hip_bf16.h>
#include <cstdint>
#include <cstddef>

// Problem constants: x[8192,4096]f32, Wp[4096,2048]i32(1 byte each),
// scales[4096,32]f32, group=128, out[8192,4096]f32.
#define TOKENS 8192
#define IN_F   4096
#define OUT_F  4096

typedef __bf16 bf16;
typedef bf16  bf16x8  __attribute__((ext_vector_type(8)));
typedef float f32x16  __attribute__((ext_vector_type(16)));

// ---------------- merged pre-pass: x f32->bf16 AND int4 W -> bf16 ----------------
__global__ void prep_kernel(const float* __restrict__ xin, bf16* __restrict__ xout,
                            const int* __restrict__ wp, const float* __restrict__ sc,
                            bf16* __restrict__ wout) {
    if (blockIdx.x < 16384) {
        size_t i = ((size_t)blockIdx.x * 256 + threadIdx.x) * 8;
        const float4* p = (const float4*)(xin + i);
        float4 a = p[0], b = p[1];
        bf16x8 r;
        r[0] = (bf16)a.x; r[1] = (bf16)a.y; r[2] = (bf16)a.z; r[3] = (bf16)a.w;
        r[4] = (bf16)b.x; r[5] = (bf16)b.y; r[6] = (bf16)b.z; r[7] = (bf16)b.w;
        *(bf16x8*)(xout + i) = r;
    } else {
        int t  = (blockIdx.x - 16384) * 256 + threadIdx.x;
        int j0 = t << 2;
        int n  = j0 >> 11;
        int g  = (j0 & 2047) >> 6;
        float s = sc[(n << 5) + g];
        int4 p = *(const int4*)(wp + j0);
        bf16x8 r;
        r[0] = (bf16)((float)((p.x & 15) - 8) * s);
        r[1] = (bf16)((float)(((p.x >> 4) & 15) - 8) * s);
        r[2] = (bf16)((float)((p.y & 15) - 8) * s);
        r[3] = (bf16)((float)(((p.y >> 4) & 15) - 8) * s);
        r[4] = (bf16)((float)((p.z & 15) - 8) * s);
        r[5] = (bf16)((float)(((p.z >> 4) & 15) - 8) * s);
        r[6] = (bf16)((float)((p.w & 15) - 8) * s);
        r[7] = (bf16)((float)(((p.w >> 4) & 15) - 8) * s);
        *(bf16x8*)(wout + ((size_t)j0 << 1)) = r;
    }
}

// ---------------- main GEMM: C[M,N] = A[M,K]_bf16 * B[N,K]_bf16^T ----------------
// BM=256, BN=128, BK=64. 256 threads = 4 waves (2m x 2n), wave tile 128x64 as
// 4x2 of 32x32x16 MFMAs (acc = 8 x f32x16 = 128 AGPRs).
// Rationale vs round 2 (LDS-pipe-bound at 84 B/cyc): LDS bytes/FLOP = (1/Mw+1/Nw);
// 128x64 wave tile is 0.75x the LDS traffic of 64x64, and 32x32x16 MFMA runs the
// matrix pipe 17% faster per FLOP than 16x16x32 (m119), dropping the MFMA floor
// below the new LDS time.
// XOR swizzle (round-2-verified, 0 conflicts): LDS slot (row, s) holds global
// chunk (row, s ^ (row&7)); swizzle applied on the GLOBAL address side since
// global_load_lds dest must be wave-uniform base + lane*16.
__global__ void __launch_bounds__(256, 2)
gemm_kernel(const bf16* __restrict__ A, const bf16* __restrict__ B,
            float* __restrict__ C) {
    __shared__ char smem[49152] __attribute__((aligned(128)));  // sA 32KB | sB 16KB

    const int tid  = threadIdx.x;
    const int lane = tid & 63;
    const int w    = tid >> 6;
    const int mt   = blockIdx.x >> 5;   // 32 M-tiles (8192/256)
    const int nt   = blockIdx.x & 31;   // 32 N-tiles (4096/128)

    // staging: per round, 256 threads fill 256 16B-chunks (32 rows x 8 chunks).
    // chunk c = r*256 + tid -> row = r*32 + (tid>>3), swizzled global chunk g.
    const int grow = tid >> 3;                    // row within a 32-row round
    const int gsw  = (tid & 7) ^ (grow & 7);      // swizzled chunk in 128B row-block
    const char* gaBase = (const char*)A + ((size_t)(mt * 256 + grow) * IN_F + gsw * 8) * 2;
    const char* gbBase = (const char*)B + ((size_t)(nt * 128 + grow) * IN_F + gsw * 8) * 2;

    const int lm   = lane & 31;
    const int half = lane >> 5;
    const int sw   = lm & 7;            // read-side swizzle key (row&7 == lm&7)
    const int raBase = (w >> 1) * 128 + lm;   // + i*32
    const int rbBase = (w & 1) * 64 + lm;     // + j*32

    f32x16 acc[4][2];
#pragma unroll
    for (int i = 0; i < 4; ++i)
#pragma unroll
        for (int j = 0; j < 2; ++j) acc[i][j] = (f32x16)0.0f;

    const bf16x8* sAv = (const bf16x8*)smem;            // 2048 chunks
    const bf16x8* sBv = (const bf16x8*)(smem + 32768);  // 1024 chunks

    for (int kt = 0; kt < IN_F / 64; ++kt) {
        const int kb = kt * 128;   // byte offset along K (64 bf16)
#pragma unroll
        for (int r = 0; r < 8; ++r)   // sA: 8 rounds of 32 rows
            __builtin_amdgcn_global_load_lds(
                (const __attribute__((address_space(1))) void*)(gaBase + (size_t)r * 32 * (IN_F * 2) + kb),
                (__attribute__((address_space(3))) void*)(smem + r * 4096 + w * 1024), 16, 0, 0);
#pragma unroll
        for (int r = 0; r < 4; ++r)   // sB: 4 rounds of 32 rows
            __builtin_amdgcn_global_load_lds(
                (const __attribute__((address_space(1))) void*)(gbBase + (size_t)r * 32 * (IN_F * 2) + kb),
                (__attribute__((address_space(3))) void*)(smem + 32768 + r * 4096 + w * 1024), 16, 0, 0);
        __syncthreads();

#pragma unroll
        for (int h = 0; h < 4; ++h) {          // K=16 per h-step
            const int slot = (h * 2 + half) ^ sw;
            bf16x8 af[4], bfr[2];
#pragma unroll
            for (int i = 0; i < 4; ++i)
                af[i] = sAv[(raBase + i * 32) * 8 + slot];
#pragma unroll
            for (int j = 0; j < 2; ++j)
                bfr[j] = sBv[(rbBase + j * 32) * 8 + slot];
#pragma unroll
            for (int i = 0; i < 4; ++i)
#pragma unroll
                for (int j = 0; j < 2; ++j)
                    acc[i][j] = __builtin_amdgcn_mfma_f32_32x32x16_bf16(af[i], bfr[j], acc[i][j], 0, 0, 0);
        }
        __syncthreads();
    }

    // epilogue: 32x32 C/D layout col=lane&31, row=(reg&3)+8*(reg>>2)+4*(lane>>5)
    // (m74/m101-verified)
    const int crowBase = mt * 256 + (w >> 1) * 128 + half * 4;
    const int ccolBase = nt * 128 + (w & 1) * 64 + lm;
#pragma unroll
    for (int i = 0; i < 4; ++i)
#pragma unroll
        for (int j = 0; j < 2; ++j)
#pragma unroll
            for (int r = 0; r < 16; ++r) {
                int row = crowBase + i * 32 + (r & 3) + 8 * (r >> 2);
                C[(size_t)row * OUT_F + ccolBase + j * 32] = acc[i][j][r];
            }
}

// ---------------- fallback (only if ws too small): slow but correct ----------------
__global__ void naive_kernel(const float* __restrict__ x, const int* __restrict__ wp,
                             const float* __restrict__ sc, float* __restrict__ out) {
    int o = blockIdx.x * 256 + threadIdx.x;
    int t = o >> 12, n = o & 4095;
    const float* xr = x + (size_t)t * IN_F;
    const int*   wr = wp + (size_t)n * (IN_F / 2);
    float acc = 0.f;
    for (int g = 0; g < 32; ++g) {
        float s = sc[n * 32 + g];
        float part = 0.f;
        for (int j = 0; j < 64; ++j) {
            int p = wr[g * 64 + j];
            part += xr[g * 128 + 2 * j]     * (float)((p & 15) - 8);
            part += xr[g * 128 + 2 * j + 1] * (float)(((p >> 4) & 15) - 8);
        }
        acc += part * s;
    }
    out[o] = acc;
}

extern "C" void kernel_launch(void* const* d_in, const int* in_sizes, int n_in,
                              void* d_out, int out_size, void* d_ws, size_t ws_size,
                              hipStream_t stream) {
    const float* x  = (const float*)d_in[0];
    const int*   wp = (const int*)d_in[1];
    const float* sc = (const float*)d_in[2];
    float* out = (float*)d_out;

    const size_t xb_bytes = (size_t)TOKENS * IN_F * 2;   // 64 MiB
    const size_t wb_bytes = (size_t)OUT_F * IN_F * 2;    // 32 MiB

    if (ws_size >= xb_bytes + wb_bytes) {
        bf16* xb = (bf16*)d_ws;
        bf16* wb = (bf16*)((char*)d_ws + xb_bytes);
        prep_kernel<<<dim3(16384 + 8192), dim3(256), 0, stream>>>(x, xb, wp, sc, wb);
        gemm_kernel<<<dim3((TOKENS / 256) * (OUT_F / 128)), dim3(256), 0, stream>>>(xb, wb, out);
    } else {
        naive_kernel<<<dim3((TOKENS * OUT_F) / 256), dim3(256), 0, stream>>>(x, wp, sc, out);
    }
}